// Round 15
// baseline (12195.624 us; speedup 1.0000x reference)
//
#include <hip/hip_runtime.h>

#define NHID 1024
#define NB   128
#define NIN  64
#define TSTEPS 512
#define NBLK 128
#define NTHR 512
#define GROW 8                  // batch rows per group
#define BCOL 128                // hidden cols per block
#define SLOTN (NB * NHID)       // elements per exchange slot

typedef __attribute__((ext_vector_type(8))) short short8v;
typedef __attribute__((ext_vector_type(4))) float f32x4;
typedef __attribute__((ext_vector_type(4))) unsigned u32x4;

__device__ __forceinline__ short8v ld8(const unsigned short* p) {
  return *reinterpret_cast<const short8v*>(p);
}

__device__ __forceinline__ unsigned short f2b(float x) {
  union { float f; unsigned u; } v; v.f = x;
  unsigned r = v.u + 0x7fffu + ((v.u >> 16) & 1u);
  return (unsigned short)(r >> 16);
}

// Unit validity: poison 0xFFFF is unforgeable (|h|,|s| < 1 strictly).
__device__ __forceinline__ bool ok16(u32x4 v) {
  unsigned bad = 0;
#pragma unroll
  for (int i = 0; i < 4; ++i) {
    bad |= (unsigned)((v[i] & 0xFFFFu) == 0xFFFFu);
    bad |= (unsigned)((v[i] >> 16) == 0xFFFFu);
  }
  return bad == 0;
}

struct GruParams {
  const unsigned short* u;                    // [T][B][NIN] bf16
  const unsigned short* WhzT; const unsigned short* WhrT; const unsigned short* WhhT; // [n][k]
  const unsigned short* WuzT; const unsigned short* WurT; const unsigned short* WuhT; // [n][k]
  const float* bz; const float* br; const float* bh;
  float* h;                                   // [B][NHID] f32 — final h only
  unsigned short* hb;                         // [4][16 rg][1024 col][8 row] bf16 h slots
  unsigned short* sb;                         // same layout, r*h slots
};

// Block = 8 batch rows (rg of 16) x 128 hidden cols (cgB of 8); 8 waves, each
// wave = 16 cols x FULL K=1024 with ALL weights register-resident:
// 3 x 32 x short8v = 384 VGPRs (launch_bounds(512,1) -> 512-VGPR budget,
// 2 waves/SIMD). R13 failed here ONLY because it streamed weights (VGPR=60).
// Wave's MFMA acc IS the finished gate pre-activation: no red[], no K-half
// handoff, ONE barrier/phase. Group = 8 blocks (convoy max over 8, was 16).
// Exchange: R14-proven flavors — col-major [col][8row] slots, 16B sc0sc1
// polls, 8B agent atomic-exchange data commit, 16B sc0sc1 poison.
__global__ __launch_bounds__(NTHR, 1) void gru_main(GruParams p) {
  __shared__ unsigned short stage[GROW * NHID];  // 16KB staged rows (swizzled row-major)

  const int tid  = threadIdx.x;
  const int lane = tid & 63;
  const int w    = tid >> 6;          // wave id 0..7 -> 16-col tile
  const int rg   = blockIdx.x >> 3;   // 16 row groups (8 rows each)
  const int cgB  = blockIdx.x & 7;    // 8 col blocks (128 cols each)
  const int lr   = lane & 15;
  const int ar_  = lr & 7;            // aliased A-row for 8-row tiles
  const int lk   = (lane >> 4) * 8;

  const int colN = cgB * BCOL + w * 16 + lr;     // this lane's output col
  const unsigned short* wz  = p.WhzT + (size_t)colN * NHID + lk;
  const unsigned short* wr  = p.WhrT + (size_t)colN * NHID + lk;
  const unsigned short* wh  = p.WhhT + (size_t)colN * NHID + lk;
  const unsigned short* wuz = p.WuzT + colN * NIN + lk;
  const unsigned short* wur = p.WurT + colN * NIN + lk;
  const unsigned short* wuh = p.WuhT + colN * NIN + lk;

  const int orow0 = (lane >> 4) * 4;  // D rows (lane>>4)*4+i; real rows < 8
  const bool owner = orow0 < GROW;    // lanes 0..31
  const float bzv = p.bz[colN];
  const float brv = p.br[colN];
  const float bhv = p.bh[colN];

  const u32x4 poisonv = {0xFFFFFFFFu, 0xFFFFFFFFu, 0xFFFFFFFFu, 0xFFFFFFFFu};

  // Full-K loop-invariant weight fragments -> registers (static indexing only —
  // rule #20; any runtime index here demotes 384 regs to scratch = disaster).
  short8v Wz[32], Wr[32], Wh[32];
#pragma unroll
  for (int it = 0; it < 32; ++it) {
    Wz[it] = ld8(wz + it * 32);
    Wr[it] = ld8(wr + it * 32);
    Wh[it] = ld8(wh + it * 32);
  }

  float h_own[4] = {0.f, 0.f, 0.f, 0.f};
  float zreg[4];

  // Poll-stage from col-major slice: unit = col (16B = 8 rows). 512 thr x 2
  // units, coalesced 16B sc0sc1 polls until non-poison (each 8B half is one
  // producer's atomic -> tearing-safe), then transpose-scatter into swizzled
  // row-major LDS.
#define PSTAGE(SRC)                                                              \
  {                                                                              \
    int j0 = tid, j1 = tid + NTHR;                                               \
    const unsigned short* g0 = (SRC) + j0 * 8;                                   \
    const unsigned short* g1 = (SRC) + j1 * 8;                                   \
    u32x4 v0 = poisonv, v1 = poisonv;                                            \
    bool k0 = false, k1 = false;                                                 \
    for (int spin = 0; spin < (1 << 13); ++spin) {                               \
      if (!k0) asm volatile("global_load_dwordx4 %0, %1, off sc0 sc1"            \
                            : "=v"(v0) : "v"(g0) : "memory");                    \
      if (!k1) asm volatile("global_load_dwordx4 %0, %1, off sc0 sc1"            \
                            : "=v"(v1) : "v"(g1) : "memory");                    \
      asm volatile("s_waitcnt vmcnt(0)" ::: "memory");                           \
      k0 = k0 || ok16(v0);                                                       \
      k1 = k1 || ok16(v1);                                                       \
      if (k0 && k1) break;                                                       \
    }                                                                            \
    _Pragma("unroll")                                                            \
    for (int r = 0; r < 8; ++r) {                                                \
      unsigned short a0 = (unsigned short)(v0[r >> 1] >> ((r & 1) * 16));        \
      unsigned short a1 = (unsigned short)(v1[r >> 1] >> ((r & 1) * 16));        \
      *(unsigned short*)((char*)stage + ((r * 2048) | ((j0 * 2) ^ (r << 4)))) = a0; \
      *(unsigned short*)((char*)stage + ((r * 2048) | ((j1 * 2) ^ (r << 4)))) = a1; \
    }                                                                            \
  }

  // Re-poison own 128-col slice of a consumed slot (contiguous 2KB in
  // col-major). Issue-only; drained by the barrier / next PSTAGE vmcnt(0) —
  // slot sP isn't rewritten for 3 more steps.
#define REPOISON(SLOTSLICE)                                                      \
  if (tid < 128) {                                                               \
    void* rp = (char*)(SLOTSLICE) + cgB * 2048 + tid * 16;                       \
    asm volatile("global_store_dwordx4 %0, %1, off sc0 sc1"                      \
                 :: "v"(rp), "v"(poisonv) : "memory");                           \
  }

#define LDSA(IT)                                                                \
  (*(const short8v*)((const char*)stage +                                       \
     ((ar_ * 2048) | ((((IT) * 32 + lk) * 2) ^ (ar_ << 4)))))

  for (int t = 0; t < TSTEPS; ++t) {
    const int sA = t & 3;          // slot holding h(t) / receiving s(t)
    const int sP = (t + 3) & 3;    // slot to re-poison (provably consumed)
    const int sW = (t + 1) & 3;    // slot receiving h(t+1)
    const unsigned short* au = p.u + ((size_t)t * NB + rg * GROW + ar_) * NIN + lk;
    unsigned short* hbR = p.hb + (size_t)sA * SLOTN + rg * GROW * NHID;
    unsigned short* sbR = p.sb + (size_t)sA * SLOTN + rg * GROW * NHID;

    // ======== phase A: z, r, s = r*h ========
    f32x4 az = {0.f, 0.f, 0.f, 0.f};
    f32x4 ar = {0.f, 0.f, 0.f, 0.f};
#pragma unroll
    for (int it = 0; it < 2; ++it) {                 // u-proj overlaps the poll
      short8v a = ld8(au + it * 32);
      az = __builtin_amdgcn_mfma_f32_16x16x32_bf16(a, ld8(wuz + it * 32), az, 0, 0, 0);
      ar = __builtin_amdgcn_mfma_f32_16x16x32_bf16(a, ld8(wur + it * 32), ar, 0, 0, 0);
    }
    PSTAGE(hbR);                                     // h(t) poll+stage
    REPOISON(p.sb + (size_t)sP * SLOTN + rg * GROW * NHID);  // retire s slot t+3
    __syncthreads();                                 // stage ready (only barrier)

#pragma unroll
    for (int it = 0; it < 32; ++it) {                // full K=1024
      short8v a = LDSA(it);
      az = __builtin_amdgcn_mfma_f32_16x16x32_bf16(a, Wz[it], az, 0, 0, 0);
      ar = __builtin_amdgcn_mfma_f32_16x16x32_bf16(a, Wr[it], ar, 0, 0, 0);
    }
    if (owner) {
      unsigned long long sd = 0;
#pragma unroll
      for (int i = 0; i < 4; ++i) {
        float z = 1.f / (1.f + __expf(-(az[i] + bzv)));
        float r = 1.f / (1.f + __expf(-(ar[i] + brv)));
        zreg[i] = z;
        sd |= (unsigned long long)f2b(r * h_own[i]) << (16 * i);
      }
      // ONE 8B atomic exchange commits rows orow0..+3 of col colN (MALL RMW)
      (void)__hip_atomic_exchange((unsigned long long*)(sbR + colN * 8 + orow0),
                                  sd, __ATOMIC_RELAXED, __HIP_MEMORY_SCOPE_AGENT);
    }

    // ======== phase B: h_tilde, h(t+1) ========
    f32x4 ac0 = {0.f, 0.f, 0.f, 0.f};
    f32x4 ac1 = {0.f, 0.f, 0.f, 0.f};
#pragma unroll
    for (int it = 0; it < 2; ++it) {
      ac0 = __builtin_amdgcn_mfma_f32_16x16x32_bf16(ld8(au + it * 32), ld8(wuh + it * 32), ac0, 0, 0, 0);
    }
    PSTAGE(sbR);                                     // s(t) poll+stage
    REPOISON(p.hb + (size_t)sP * SLOTN + rg * GROW * NHID);  // retire h slot t+3
    __syncthreads();

#pragma unroll
    for (int it = 0; it < 32; it += 2) {             // 2 chains break MFMA dep
      ac0 = __builtin_amdgcn_mfma_f32_16x16x32_bf16(LDSA(it), Wh[it], ac0, 0, 0, 0);
      ac1 = __builtin_amdgcn_mfma_f32_16x16x32_bf16(LDSA(it + 1), Wh[it + 1], ac1, 0, 0, 0);
    }
    if (owner) {
      unsigned long long hd = 0;
#pragma unroll
      for (int i = 0; i < 4; ++i) {
        float x = ac0[i] + ac1[i] + bhv;
        float e = __expf(2.f * x);
        float ht = 1.f - 2.f / (e + 1.f);            // tanh, overflow-safe
        float hn = (1.f - zreg[i]) * h_own[i] + zreg[i] * ht;
        h_own[i] = hn;
        hd |= (unsigned long long)f2b(hn) << (16 * i);
      }
      unsigned short* hbW = p.hb + (size_t)sW * SLOTN + rg * GROW * NHID;
      (void)__hip_atomic_exchange((unsigned long long*)(hbW + colN * 8 + orow0),
                                  hd, __ATOMIC_RELAXED, __HIP_MEMORY_SCOPE_AGENT);
      if (t == TSTEPS - 1) {
#pragma unroll
        for (int i = 0; i < 4; ++i)
          p.h[(size_t)(rg * GROW + orow0 + i) * NHID + colN] = h_own[i];
      }
    }
  }
#undef PSTAGE
#undef REPOISON
#undef LDSA
}

// out[c*R + r] = bf16(in[r*C + c])  (W[k][n] -> WT[n][k])
__global__ void k_transpose_bf16(const float* in, unsigned short* out, int R, int C) {
  int idx = blockIdx.x * 256 + threadIdx.x;
  if (idx < R * C) {
    int r = idx / C, c = idx % C;
    out[(size_t)c * R + r] = f2b(in[idx]);
  }
}

__global__ void k_convert_bf16(const float* in, unsigned short* out, int n) {
  for (int i = blockIdx.x * 256 + threadIdx.x; i < n; i += gridDim.x * 256)
    out[i] = f2b(in[i]);
}

// logits = h_final @ W_hy + b_y ; one block (64 lanes) per batch row
__global__ void k_logits(const float* __restrict__ h, const float* __restrict__ Why,
                         const float* __restrict__ by, float* __restrict__ out) {
  int row = blockIdx.x;
  int lane = threadIdx.x;
  float acc[10];
#pragma unroll
  for (int j = 0; j < 10; ++j) acc[j] = 0.f;
  for (int k = lane; k < NHID; k += 64) {
    float hv = h[row * NHID + k];
#pragma unroll
    for (int j = 0; j < 10; ++j) acc[j] += hv * Why[k * 10 + j];
  }
#pragma unroll
  for (int j = 0; j < 10; ++j)
    for (int off = 32; off; off >>= 1) acc[j] += __shfl_down(acc[j], off);
  if (lane == 0) {
#pragma unroll
    for (int j = 0; j < 10; ++j) out[row * 10 + j] = acc[j] + by[j];
  }
}

extern "C" void kernel_launch(void* const* d_in, const int* in_sizes, int n_in,
                              void* d_out, int out_size, void* d_ws, size_t ws_size,
                              hipStream_t stream) {
  (void)in_sizes; (void)n_in; (void)out_size; (void)ws_size;
  const float* u   = (const float*)d_in[0];
  const float* Wuz = (const float*)d_in[1];
  const float* Whz = (const float*)d_in[2];
  const float* bz  = (const float*)d_in[3];
  const float* Wur = (const float*)d_in[4];
  const float* Whr = (const float*)d_in[5];
  const float* br  = (const float*)d_in[6];
  const float* Wuh = (const float*)d_in[7];
  const float* Whh = (const float*)d_in[8];
  const float* bh  = (const float*)d_in[9];
  const float* Why = (const float*)d_in[10];
  const float* by  = (const float*)d_in[11];

  char* ws = (char*)d_ws;
  size_t off = 0;
  auto alloc = [&](size_t bytes) { char* p = ws + off; off += (bytes + 255) & ~255ull; return p; };
  unsigned short* WhzT = (unsigned short*)alloc((size_t)NHID * NHID * 2);
  unsigned short* WhrT = (unsigned short*)alloc((size_t)NHID * NHID * 2);
  unsigned short* WhhT = (unsigned short*)alloc((size_t)NHID * NHID * 2);
  unsigned short* WuzT = (unsigned short*)alloc((size_t)NHID * NIN * 2);
  unsigned short* WurT = (unsigned short*)alloc((size_t)NHID * NIN * 2);
  unsigned short* WuhT = (unsigned short*)alloc((size_t)NHID * NIN * 2);
  unsigned short* ub   = (unsigned short*)alloc((size_t)TSTEPS * NB * NIN * 2);
  unsigned short* hb   = (unsigned short*)alloc(4ull * SLOTN * 2);
  unsigned short* sb   = (unsigned short*)alloc(4ull * SLOTN * 2);

  float* out = (float*)d_out;
  float* hf  = out + NB * 10;   // h_final region of d_out

  int n1 = NHID * NHID;
  hipLaunchKernelGGL(k_transpose_bf16, dim3((n1 + 255) / 256), dim3(256), 0, stream, Whz, WhzT, NHID, NHID);
  hipLaunchKernelGGL(k_transpose_bf16, dim3((n1 + 255) / 256), dim3(256), 0, stream, Whr, WhrT, NHID, NHID);
  hipLaunchKernelGGL(k_transpose_bf16, dim3((n1 + 255) / 256), dim3(256), 0, stream, Whh, WhhT, NHID, NHID);
  int n2 = NIN * NHID;
  hipLaunchKernelGGL(k_transpose_bf16, dim3((n2 + 255) / 256), dim3(256), 0, stream, Wuz, WuzT, NIN, NHID);
  hipLaunchKernelGGL(k_transpose_bf16, dim3((n2 + 255) / 256), dim3(256), 0, stream, Wur, WurT, NIN, NHID);
  hipLaunchKernelGGL(k_transpose_bf16, dim3((n2 + 255) / 256), dim3(256), 0, stream, Wuh, WuhT, NIN, NHID);
  int n3 = TSTEPS * NB * NIN;
  hipLaunchKernelGGL(k_convert_bf16, dim3(2048), dim3(256), 0, stream, u, ub, n3);
  // Slot init each launch (deterministic under graph replay):
  // hb slot 0 = real h0 = 0; hb slots 1-3 and all sb slots = 0xFFFF poison.
  hipMemsetAsync(hb, 0, (size_t)SLOTN * 2, stream);
  hipMemsetAsync(hb + SLOTN, 0xFF, 3ull * SLOTN * 2, stream);
  hipMemsetAsync(sb, 0xFF, 4ull * SLOTN * 2, stream);

  GruParams p;
  p.u = ub; p.WhzT = WhzT; p.WhrT = WhrT; p.WhhT = WhhT;
  p.WuzT = WuzT; p.WurT = WurT; p.WuhT = WuhT;
  p.bz = bz; p.br = br; p.bh = bh;
  p.h = hf; p.hb = hb; p.sb = sb;
  hipLaunchKernelGGL(gru_main, dim3(NBLK), dim3(NTHR), 0, stream, p);

  hipLaunchKernelGGL(k_logits, dim3(NB), dim3(64), 0, stream, hf, Why, by, out);
}

// Round 16
// 3781.557 us; speedup vs baseline: 3.2250x; 3.2250x over previous
//
#include <hip/hip_runtime.h>

#define NHID 1024
#define NB   128
#define NIN  64
#define TSTEPS 512
#define NBLK 256
#define NTHR 256
#define GROW 8                  // batch rows per group
#define BCOL 64                 // hidden cols per block
#define SLOTN (NB * NHID)       // elements per exchange slot

typedef __attribute__((ext_vector_type(8))) short short8v;
typedef __attribute__((ext_vector_type(4))) float f32x4;
typedef __attribute__((ext_vector_type(4))) unsigned u32x4;

__device__ __forceinline__ short8v ld8(const unsigned short* p) {
  return *reinterpret_cast<const short8v*>(p);
}

__device__ __forceinline__ unsigned short f2b(float x) {
  union { float f; unsigned u; } v; v.f = x;
  unsigned r = v.u + 0x7fffu + ((v.u >> 16) & 1u);
  return (unsigned short)(r >> 16);
}

// Unit validity: poison 0xFFFF is unforgeable (|h|,|s| < 1 strictly).
__device__ __forceinline__ bool ok16(u32x4 v) {
  unsigned bad = 0;
#pragma unroll
  for (int i = 0; i < 4; ++i) {
    bad |= (unsigned)((v[i] & 0xFFFFu) == 0xFFFFu);
    bad |= (unsigned)((v[i] >> 16) == 0xFFFFu);
  }
  return bad == 0;
}

struct GruParams {
  const unsigned short* u;                    // [T][B][NIN] bf16
  const unsigned short* WhzT; const unsigned short* WhrT; const unsigned short* WhhT; // [n][k]
  const unsigned short* WuzT; const unsigned short* WurT; const unsigned short* WuhT; // [n][k]
  const float* bz; const float* br; const float* bh;
  float* h;                                   // [B][NHID] f32 — final h only
  unsigned short* hb;                         // [4][16 rg][1024 col][8 row] bf16 h slots
  unsigned short* sb;                         // same layout, r*h slots
};

// Block = 8 batch rows (rg of 16) x 64 hidden cols (cg of 16); 4 waves of a
// 256-THREAD block, each wave = 16 cols x FULL K=1024 with all weights
// register-resident. REGISTER ARITHMETIC (R15's failure): 512-thr block = 8
// waves / 4 SIMDs = 2 waves/SIMD -> 256-reg cap -> 384 weight regs spill.
// 256-thr block = 4 waves = 1 wave/SIMD -> 512-reg unified budget: 384 weight
// frags (VGPR+AGPR) + ~80 working fits. Wave's MFMA acc IS the finished gate
// pre-activation: no red[], no K-half handoff, ONE barrier/phase.
// Exchange: R14-proven flavors — col-major [col][8row] slots, 16B sc0sc1
// polls, 8B agent atomic-exchange data commit, 16B sc0sc1 poison.
__global__ __launch_bounds__(NTHR, 1) void gru_main(GruParams p) {
  __shared__ unsigned short stage[GROW * NHID];  // 16KB staged rows (swizzled row-major)

  const int tid  = threadIdx.x;
  const int lane = tid & 63;
  const int w    = tid >> 6;          // wave id 0..3 -> 16-col tile
  const int rg   = blockIdx.x >> 4;   // 16 row groups (8 rows each)
  const int cg   = blockIdx.x & 15;   // 16 col groups (64 cols each)
  const int lr   = lane & 15;
  const int ar_  = lr & 7;            // aliased A-row for 8-row tiles
  const int lk   = (lane >> 4) * 8;

  const int colN = cg * BCOL + w * 16 + lr;      // this lane's output col
  const unsigned short* wz  = p.WhzT + (size_t)colN * NHID + lk;
  const unsigned short* wr  = p.WhrT + (size_t)colN * NHID + lk;
  const unsigned short* wh  = p.WhhT + (size_t)colN * NHID + lk;
  const unsigned short* wuz = p.WuzT + colN * NIN + lk;
  const unsigned short* wur = p.WurT + colN * NIN + lk;
  const unsigned short* wuh = p.WuhT + colN * NIN + lk;

  const int orow0 = (lane >> 4) * 4;  // D rows (lane>>4)*4+i; real rows < 8
  const bool owner = orow0 < GROW;    // lanes 0..31 of each wave
  const float bzv = p.bz[colN];
  const float brv = p.br[colN];
  const float bhv = p.bh[colN];

  const u32x4 poisonv = {0xFFFFFFFFu, 0xFFFFFFFFu, 0xFFFFFFFFu, 0xFFFFFFFFu};

  // Full-K loop-invariant weight fragments -> unified VGPR/AGPR file (static
  // indexing only — rule #20; runtime index demotes 384 regs to scratch).
  short8v Wz[32], Wr[32], Wh[32];
#pragma unroll
  for (int it = 0; it < 32; ++it) {
    Wz[it] = ld8(wz + it * 32);
    Wr[it] = ld8(wr + it * 32);
    Wh[it] = ld8(wh + it * 32);
  }

  float h_own[4] = {0.f, 0.f, 0.f, 0.f};
  float zreg[4];

  // Poll-stage from col-major slice: unit = col (16B = 8 rows). 256 thr x 4
  // units, coalesced 16B sc0sc1 polls until non-poison (each 8B half is one
  // producer's atomic -> tearing-safe), then transpose-scatter into swizzled
  // row-major LDS.
#define PSTAGE(SRC)                                                              \
  {                                                                              \
    int j0 = tid, j1 = tid + NTHR, j2 = tid + 2 * NTHR, j3 = tid + 3 * NTHR;     \
    const unsigned short* g0 = (SRC) + j0 * 8;                                   \
    const unsigned short* g1 = (SRC) + j1 * 8;                                   \
    const unsigned short* g2 = (SRC) + j2 * 8;                                   \
    const unsigned short* g3 = (SRC) + j3 * 8;                                   \
    u32x4 v0 = poisonv, v1 = poisonv, v2 = poisonv, v3 = poisonv;                \
    bool k0 = false, k1 = false, k2 = false, k3 = false;                         \
    for (int spin = 0; spin < (1 << 13); ++spin) {                               \
      if (!k0) asm volatile("global_load_dwordx4 %0, %1, off sc0 sc1"            \
                            : "=v"(v0) : "v"(g0) : "memory");                    \
      if (!k1) asm volatile("global_load_dwordx4 %0, %1, off sc0 sc1"            \
                            : "=v"(v1) : "v"(g1) : "memory");                    \
      if (!k2) asm volatile("global_load_dwordx4 %0, %1, off sc0 sc1"            \
                            : "=v"(v2) : "v"(g2) : "memory");                    \
      if (!k3) asm volatile("global_load_dwordx4 %0, %1, off sc0 sc1"            \
                            : "=v"(v3) : "v"(g3) : "memory");                    \
      asm volatile("s_waitcnt vmcnt(0)" ::: "memory");                           \
      k0 = k0 || ok16(v0);                                                       \
      k1 = k1 || ok16(v1);                                                       \
      k2 = k2 || ok16(v2);                                                       \
      k3 = k3 || ok16(v3);                                                       \
      if (k0 && k1 && k2 && k3) break;                                           \
    }                                                                            \
    _Pragma("unroll")                                                            \
    for (int r = 0; r < 8; ++r) {                                                \
      unsigned short a0 = (unsigned short)(v0[r >> 1] >> ((r & 1) * 16));        \
      unsigned short a1 = (unsigned short)(v1[r >> 1] >> ((r & 1) * 16));        \
      unsigned short a2 = (unsigned short)(v2[r >> 1] >> ((r & 1) * 16));        \
      unsigned short a3 = (unsigned short)(v3[r >> 1] >> ((r & 1) * 16));        \
      *(unsigned short*)((char*)stage + ((r * 2048) | ((j0 * 2) ^ (r << 4)))) = a0; \
      *(unsigned short*)((char*)stage + ((r * 2048) | ((j1 * 2) ^ (r << 4)))) = a1; \
      *(unsigned short*)((char*)stage + ((r * 2048) | ((j2 * 2) ^ (r << 4)))) = a2; \
      *(unsigned short*)((char*)stage + ((r * 2048) | ((j3 * 2) ^ (r << 4)))) = a3; \
    }                                                                            \
  }

  // Re-poison own 64-col slice of a consumed slot (contiguous 1KB col-major).
  // Issue-only; drained by the next barrier — slot sP idle for 3 more steps.
#define REPOISON(SLOTSLICE)                                                      \
  if (tid < 64) {                                                                \
    void* rp = (char*)(SLOTSLICE) + cg * 1024 + tid * 16;                        \
    asm volatile("global_store_dwordx4 %0, %1, off sc0 sc1"                      \
                 :: "v"(rp), "v"(poisonv) : "memory");                           \
  }

#define LDSA(IT)                                                                \
  (*(const short8v*)((const char*)stage +                                       \
     ((ar_ * 2048) | ((((IT) * 32 + lk) * 2) ^ (ar_ << 4)))))

  for (int t = 0; t < TSTEPS; ++t) {
    const int sA = t & 3;          // slot holding h(t) / receiving s(t)
    const int sP = (t + 3) & 3;    // slot to re-poison (provably consumed)
    const int sW = (t + 1) & 3;    // slot receiving h(t+1)
    const unsigned short* au = p.u + ((size_t)t * NB + rg * GROW + ar_) * NIN + lk;
    unsigned short* hbR = p.hb + (size_t)sA * SLOTN + rg * GROW * NHID;
    unsigned short* sbR = p.sb + (size_t)sA * SLOTN + rg * GROW * NHID;

    // ======== phase A: z, r, s = r*h ========
    f32x4 az0 = {0.f, 0.f, 0.f, 0.f}, az1 = {0.f, 0.f, 0.f, 0.f};
    f32x4 ar0 = {0.f, 0.f, 0.f, 0.f}, ar1 = {0.f, 0.f, 0.f, 0.f};
#pragma unroll
    for (int it = 0; it < 2; ++it) {                 // u-proj overlaps the poll
      short8v a = ld8(au + it * 32);
      az0 = __builtin_amdgcn_mfma_f32_16x16x32_bf16(a, ld8(wuz + it * 32), az0, 0, 0, 0);
      ar0 = __builtin_amdgcn_mfma_f32_16x16x32_bf16(a, ld8(wur + it * 32), ar0, 0, 0, 0);
    }
    PSTAGE(hbR);                                     // h(t) poll+stage
    REPOISON(p.sb + (size_t)sP * SLOTN + rg * GROW * NHID);  // retire s slot t+3
    __syncthreads();                                 // stage ready (only barrier)

#pragma unroll
    for (int it = 0; it < 32; it += 2) {             // full K; 4 indep chains
      short8v a0 = LDSA(it);
      short8v a1 = LDSA(it + 1);
      az0 = __builtin_amdgcn_mfma_f32_16x16x32_bf16(a0, Wz[it], az0, 0, 0, 0);
      ar0 = __builtin_amdgcn_mfma_f32_16x16x32_bf16(a0, Wr[it], ar0, 0, 0, 0);
      az1 = __builtin_amdgcn_mfma_f32_16x16x32_bf16(a1, Wz[it + 1], az1, 0, 0, 0);
      ar1 = __builtin_amdgcn_mfma_f32_16x16x32_bf16(a1, Wr[it + 1], ar1, 0, 0, 0);
    }
    if (owner) {
      unsigned long long sd = 0;
#pragma unroll
      for (int i = 0; i < 4; ++i) {
        float z = 1.f / (1.f + __expf(-(az0[i] + az1[i] + bzv)));
        float r = 1.f / (1.f + __expf(-(ar0[i] + ar1[i] + brv)));
        zreg[i] = z;
        sd |= (unsigned long long)f2b(r * h_own[i]) << (16 * i);
      }
      // ONE 8B atomic exchange commits rows orow0..+3 of col colN (MALL RMW)
      (void)__hip_atomic_exchange((unsigned long long*)(sbR + colN * 8 + orow0),
                                  sd, __ATOMIC_RELAXED, __HIP_MEMORY_SCOPE_AGENT);
    }

    // ======== phase B: h_tilde, h(t+1) ========
    f32x4 ac0 = {0.f, 0.f, 0.f, 0.f}, ac1 = {0.f, 0.f, 0.f, 0.f};
#pragma unroll
    for (int it = 0; it < 2; ++it) {
      ac0 = __builtin_amdgcn_mfma_f32_16x16x32_bf16(ld8(au + it * 32), ld8(wuh + it * 32), ac0, 0, 0, 0);
    }
    PSTAGE(sbR);                                     // s(t) poll+stage
    REPOISON(p.hb + (size_t)sP * SLOTN + rg * GROW * NHID);  // retire h slot t+3
    __syncthreads();

#pragma unroll
    for (int it = 0; it < 32; it += 2) {             // 2 indep chains
      ac0 = __builtin_amdgcn_mfma_f32_16x16x32_bf16(LDSA(it), Wh[it], ac0, 0, 0, 0);
      ac1 = __builtin_amdgcn_mfma_f32_16x16x32_bf16(LDSA(it + 1), Wh[it + 1], ac1, 0, 0, 0);
    }
    if (owner) {
      unsigned long long hd = 0;
#pragma unroll
      for (int i = 0; i < 4; ++i) {
        float x = ac0[i] + ac1[i] + bhv;
        float e = __expf(2.f * x);
        float ht = 1.f - 2.f / (e + 1.f);            // tanh, overflow-safe
        float hn = (1.f - zreg[i]) * h_own[i] + zreg[i] * ht;
        h_own[i] = hn;
        hd |= (unsigned long long)f2b(hn) << (16 * i);
      }
      unsigned short* hbW = p.hb + (size_t)sW * SLOTN + rg * GROW * NHID;
      (void)__hip_atomic_exchange((unsigned long long*)(hbW + colN * 8 + orow0),
                                  hd, __ATOMIC_RELAXED, __HIP_MEMORY_SCOPE_AGENT);
      if (t == TSTEPS - 1) {
#pragma unroll
        for (int i = 0; i < 4; ++i)
          p.h[(size_t)(rg * GROW + orow0 + i) * NHID + colN] = h_own[i];
      }
    }
  }
#undef PSTAGE
#undef REPOISON
#undef LDSA
}

// out[c*R + r] = bf16(in[r*C + c])  (W[k][n] -> WT[n][k])
__global__ void k_transpose_bf16(const float* in, unsigned short* out, int R, int C) {
  int idx = blockIdx.x * 256 + threadIdx.x;
  if (idx < R * C) {
    int r = idx / C, c = idx % C;
    out[(size_t)c * R + r] = f2b(in[idx]);
  }
}

__global__ void k_convert_bf16(const float* in, unsigned short* out, int n) {
  for (int i = blockIdx.x * 256 + threadIdx.x; i < n; i += gridDim.x * 256)
    out[i] = f2b(in[i]);
}

// logits = h_final @ W_hy + b_y ; one block (64 lanes) per batch row
__global__ void k_logits(const float* __restrict__ h, const float* __restrict__ Why,
                         const float* __restrict__ by, float* __restrict__ out) {
  int row = blockIdx.x;
  int lane = threadIdx.x;
  float acc[10];
#pragma unroll
  for (int j = 0; j < 10; ++j) acc[j] = 0.f;
  for (int k = lane; k < NHID; k += 64) {
    float hv = h[row * NHID + k];
#pragma unroll
    for (int j = 0; j < 10; ++j) acc[j] += hv * Why[k * 10 + j];
  }
#pragma unroll
  for (int j = 0; j < 10; ++j)
    for (int off = 32; off; off >>= 1) acc[j] += __shfl_down(acc[j], off);
  if (lane == 0) {
#pragma unroll
    for (int j = 0; j < 10; ++j) out[row * 10 + j] = acc[j] + by[j];
  }
}

extern "C" void kernel_launch(void* const* d_in, const int* in_sizes, int n_in,
                              void* d_out, int out_size, void* d_ws, size_t ws_size,
                              hipStream_t stream) {
  (void)in_sizes; (void)n_in; (void)out_size; (void)ws_size;
  const float* u   = (const float*)d_in[0];
  const float* Wuz = (const float*)d_in[1];
  const float* Whz = (const float*)d_in[2];
  const float* bz  = (const float*)d_in[3];
  const float* Wur = (const float*)d_in[4];
  const float* Whr = (const float*)d_in[5];
  const float* br  = (const float*)d_in[6];
  const float* Wuh = (const float*)d_in[7];
  const float* Whh = (const float*)d_in[8];
  const float* bh  = (const float*)d_in[9];
  const float* Why = (const float*)d_in[10];
  const float* by  = (const float*)d_in[11];

  char* ws = (char*)d_ws;
  size_t off = 0;
  auto alloc = [&](size_t bytes) { char* p = ws + off; off += (bytes + 255) & ~255ull; return p; };
  unsigned short* WhzT = (unsigned short*)alloc((size_t)NHID * NHID * 2);
  unsigned short* WhrT = (unsigned short*)alloc((size_t)NHID * NHID * 2);
  unsigned short* WhhT = (unsigned short*)alloc((size_t)NHID * NHID * 2);
  unsigned short* WuzT = (unsigned short*)alloc((size_t)NHID * NIN * 2);
  unsigned short* WurT = (unsigned short*)alloc((size_t)NHID * NIN * 2);
  unsigned short* WuhT = (unsigned short*)alloc((size_t)NHID * NIN * 2);
  unsigned short* ub   = (unsigned short*)alloc((size_t)TSTEPS * NB * NIN * 2);
  unsigned short* hb   = (unsigned short*)alloc(4ull * SLOTN * 2);
  unsigned short* sb   = (unsigned short*)alloc(4ull * SLOTN * 2);

  float* out = (float*)d_out;
  float* hf  = out + NB * 10;   // h_final region of d_out

  int n1 = NHID * NHID;
  hipLaunchKernelGGL(k_transpose_bf16, dim3((n1 + 255) / 256), dim3(256), 0, stream, Whz, WhzT, NHID, NHID);
  hipLaunchKernelGGL(k_transpose_bf16, dim3((n1 + 255) / 256), dim3(256), 0, stream, Whr, WhrT, NHID, NHID);
  hipLaunchKernelGGL(k_transpose_bf16, dim3((n1 + 255) / 256), dim3(256), 0, stream, Whh, WhhT, NHID, NHID);
  int n2 = NIN * NHID;
  hipLaunchKernelGGL(k_transpose_bf16, dim3((n2 + 255) / 256), dim3(256), 0, stream, Wuz, WuzT, NIN, NHID);
  hipLaunchKernelGGL(k_transpose_bf16, dim3((n2 + 255) / 256), dim3(256), 0, stream, Wur, WurT, NIN, NHID);
  hipLaunchKernelGGL(k_transpose_bf16, dim3((n2 + 255) / 256), dim3(256), 0, stream, Wuh, WuhT, NIN, NHID);
  int n3 = TSTEPS * NB * NIN;
  hipLaunchKernelGGL(k_convert_bf16, dim3(2048), dim3(256), 0, stream, u, ub, n3);
  // Slot init each launch (deterministic under graph replay):
  // hb slot 0 = real h0 = 0; hb slots 1-3 and all sb slots = 0xFFFF poison.
  hipMemsetAsync(hb, 0, (size_t)SLOTN * 2, stream);
  hipMemsetAsync(hb + SLOTN, 0xFF, 3ull * SLOTN * 2, stream);
  hipMemsetAsync(sb, 0xFF, 4ull * SLOTN * 2, stream);

  GruParams p;
  p.u = ub; p.WhzT = WhzT; p.WhrT = WhrT; p.WhhT = WhhT;
  p.WuzT = WuzT; p.WurT = WurT; p.WuhT = WuhT;
  p.bz = bz; p.br = br; p.bh = bh;
  p.h = hf; p.hb = hb; p.sb = sb;
  hipLaunchKernelGGL(gru_main, dim3(NBLK), dim3(NTHR), 0, stream, p);

  hipLaunchKernelGGL(k_logits, dim3(NB), dim3(64), 0, stream, hf, Why, by, out);
}

// Round 17
// 3558.745 us; speedup vs baseline: 3.4269x; 1.0626x over previous
//
#include <hip/hip_runtime.h>

#define NHID 1024
#define NB   128
#define NIN  64
#define TSTEPS 512
#define NBLK 256
#define NTHR 512
#define GROW 8                  // batch rows per group
#define SLOTN (NB * NHID)       // elements per exchange slot

typedef __attribute__((ext_vector_type(8))) short short8v;
typedef __attribute__((ext_vector_type(4))) float f32x4;
typedef __attribute__((ext_vector_type(4))) unsigned u32x4;

__device__ __forceinline__ short8v ld8(const unsigned short* p) {
  return *reinterpret_cast<const short8v*>(p);
}

__device__ __forceinline__ unsigned short f2b(float x) {
  union { float f; unsigned u; } v; v.f = x;
  unsigned r = v.u + 0x7fffu + ((v.u >> 16) & 1u);
  return (unsigned short)(r >> 16);
}

// Unit validity: poison 0xFFFF is unforgeable (|h|,|s| < 1 strictly).
__device__ __forceinline__ bool ok16(u32x4 v) {
  unsigned bad = 0;
#pragma unroll
  for (int i = 0; i < 4; ++i) {
    bad |= (unsigned)((v[i] & 0xFFFFu) == 0xFFFFu);
    bad |= (unsigned)((v[i] >> 16) == 0xFFFFu);
  }
  return bad == 0;
}

struct GruParams {
  const unsigned short* u;                    // [T][B][NIN] bf16
  const unsigned short* WhzT; const unsigned short* WhrT; const unsigned short* WhhT; // [n][k]
  const unsigned short* WuzT; const unsigned short* WurT; const unsigned short* WuhT; // [n][k]
  const float* bz; const float* br; const float* bh;
  float* h;                                   // [B][NHID] f32 — final h only
  unsigned short* hb;                         // [4][16 rg][1024 col][8 row] bf16 h slots
  unsigned short* sb;                         // same layout, r*h slots
};

// R14 structure (best measured: 3.56 ms): block = 8 rows x 64 cols, 8 waves
// (4 ct x 2 kh, register-resident half-K weights), 256 blocks, poison-poll
// sync, col-major exchange slots, 8B atomic-exchange commit.
// R17 deltas: (1) barrier #1 is a raw `s_waitcnt lgkmcnt(0); s_barrier` —
// __syncthreads would drain vmcnt(0), putting the just-issued poison stores'
// acks on the critical path; the poison-before-my-commit invariant is upheld
// by barrier #2 (full __syncthreads) instead, by which time the acks rode
// under the MFMA loop. (2) poll backoff s_sleep(1) after the first failed
// round — waiting threads generate ~16 TB/s of MALL poll traffic that queues
// ahead of the commits being awaited.
__global__ __launch_bounds__(NTHR, 2) void gru_main(GruParams p) {
  __shared__ unsigned short stage[GROW * NHID];  // 16KB staged rows (swizzled row-major)
  __shared__ float red[2][4][4][64];             // K-half reduction, component-major

  const int tid  = threadIdx.x;
  const int lane = tid & 63;
  const int w    = tid >> 6;
  const int ct   = w & 3;
  const int kh   = w >> 2;
  const int rg   = blockIdx.x >> 4;   // 16 row groups (8 rows each)
  const int cg   = blockIdx.x & 15;   // 16 col groups (64 cols each)
  const int lr   = lane & 15;
  const int ar_  = lr & 7;            // aliased A-row for 8-row tiles
  const int lk   = (lane >> 4) * 8;

  const int colN = cg * 64 + ct * 16 + lr;
  const unsigned short* wz  = p.WhzT + (size_t)colN * NHID + kh * 512 + lk;
  const unsigned short* wr  = p.WhrT + (size_t)colN * NHID + kh * 512 + lk;
  const unsigned short* wh  = p.WhhT + (size_t)colN * NHID + kh * 512 + lk;
  const unsigned short* wuz = p.WuzT + colN * NIN + lk;
  const unsigned short* wur = p.WurT + colN * NIN + lk;
  const unsigned short* wuh = p.WuhT + colN * NIN + lk;

  const int orow0 = (lane >> 4) * 4;  // output row base; only orow0<8 is real
  const bool owner = orow0 < GROW;    // lanes 0..31 of !kh waves
  const float bzv = p.bz[colN];
  const float brv = p.br[colN];
  const float bhv = p.bh[colN];

  const u32x4 poisonv = {0xFFFFFFFFu, 0xFFFFFFFFu, 0xFFFFFFFFu, 0xFFFFFFFFu};

  // Loop-invariant recurrent-weight B-fragments (static indexing only — rule #20).
  short8v Wz[16], Wr[16], Wh[16];
#pragma unroll
  for (int it = 0; it < 16; ++it) {
    Wz[it] = ld8(wz + it * 32);
    Wr[it] = ld8(wr + it * 32);
    Wh[it] = ld8(wh + it * 32);
  }

  float h_own[4] = {0.f, 0.f, 0.f, 0.f};
  float zreg[4];

  // Poll-stage from col-major slice: unit = col (16B = 8 rows). 512 thr x 2
  // units, coalesced 16B sc0sc1 polls until non-poison (each 8B half is one
  // producer's atomic -> tearing-safe), then transpose-scatter into swizzled
  // row-major LDS. Mild backoff after the first failed round cuts MALL
  // poll congestion (~16 TB/s chip-wide while convoying).
#define PSTAGE(SRC)                                                              \
  {                                                                              \
    int j0 = tid, j1 = tid + NTHR;                                               \
    const unsigned short* g0 = (SRC) + j0 * 8;                                   \
    const unsigned short* g1 = (SRC) + j1 * 8;                                   \
    u32x4 v0 = poisonv, v1 = poisonv;                                            \
    bool k0 = false, k1 = false;                                                 \
    for (int spin = 0; spin < (1 << 13); ++spin) {                               \
      if (!k0) asm volatile("global_load_dwordx4 %0, %1, off sc0 sc1"            \
                            : "=v"(v0) : "v"(g0) : "memory");                    \
      if (!k1) asm volatile("global_load_dwordx4 %0, %1, off sc0 sc1"            \
                            : "=v"(v1) : "v"(g1) : "memory");                    \
      asm volatile("s_waitcnt vmcnt(0)" ::: "memory");                           \
      k0 = k0 || ok16(v0);                                                       \
      k1 = k1 || ok16(v1);                                                       \
      if (k0 && k1) break;                                                       \
      if (spin >= 1) __builtin_amdgcn_s_sleep(1);                                \
    }                                                                            \
    _Pragma("unroll")                                                            \
    for (int r = 0; r < 8; ++r) {                                                \
      unsigned short a0 = (unsigned short)(v0[r >> 1] >> ((r & 1) * 16));        \
      unsigned short a1 = (unsigned short)(v1[r >> 1] >> ((r & 1) * 16));        \
      *(unsigned short*)((char*)stage + ((r * 2048) | ((j0 * 2) ^ (r << 4)))) = a0; \
      *(unsigned short*)((char*)stage + ((r * 2048) | ((j1 * 2) ^ (r << 4)))) = a1; \
    }                                                                            \
  }

  // Re-poison own 64-col slice of a consumed slot: contiguous 1KB col-major,
  // 64 x 16B stores. Issue-only — acks land during the MFMA loop; visibility
  // before my data commit is guaranteed by barrier #2 (full __syncthreads).
#define REPOISON(SLOTSLICE)                                                      \
  if (tid < 64) {                                                                \
    void* rp = (char*)(SLOTSLICE) + cg * 1024 + tid * 16;                        \
    asm volatile("global_store_dwordx4 %0, %1, off sc0 sc1"                      \
                 :: "v"(rp), "v"(poisonv) : "memory");                           \
  }

  // Barrier #1: LDS-only barrier. __syncthreads would drain vmcnt(0) and
  // serialize on the poison-store acks; we only need the ds_writes visible.
#define LDS_BARRIER()                                                            \
  asm volatile("s_waitcnt lgkmcnt(0)\n\ts_barrier" ::: "memory")

#define LDSA(IT)                                                                \
  (*(const short8v*)((const char*)stage +                                       \
     ((ar_ * 2048) | ((((kh * 512 + (IT) * 32 + lk) * 2)) ^ (ar_ << 4)))))

  for (int t = 0; t < TSTEPS; ++t) {
    const int sA = t & 3;          // slot holding h(t) / receiving s(t)
    const int sP = (t + 3) & 3;    // slot to re-poison (provably consumed)
    const int sW = (t + 1) & 3;    // slot receiving h(t+1)
    const unsigned short* au = p.u + ((size_t)t * NB + rg * GROW + ar_) * NIN + lk;
    unsigned short* hbR = p.hb + (size_t)sA * SLOTN + rg * GROW * NHID;
    unsigned short* sbR = p.sb + (size_t)sA * SLOTN + rg * GROW * NHID;

    // ======== phase A: z, r, s = r*h ========
    f32x4 az = {0.f, 0.f, 0.f, 0.f};
    f32x4 ar = {0.f, 0.f, 0.f, 0.f};
    if (kh) {        // u-projection overlaps the data poll
#pragma unroll
      for (int it = 0; it < 2; ++it) {
        short8v a = ld8(au + it * 32);
        az = __builtin_amdgcn_mfma_f32_16x16x32_bf16(a, ld8(wuz + it * 32), az, 0, 0, 0);
        ar = __builtin_amdgcn_mfma_f32_16x16x32_bf16(a, ld8(wur + it * 32), ar, 0, 0, 0);
      }
    }
    PSTAGE(hbR);                                         // h(t) poll+stage
    REPOISON(p.sb + (size_t)sP * SLOTN + rg * GROW * NHID);  // retire s slot t+3 (issue)
    LDS_BARRIER();                                       // stage ready; poison in flight

#pragma unroll
    for (int it = 0; it < 16; ++it) {
      short8v a = LDSA(it);
      az = __builtin_amdgcn_mfma_f32_16x16x32_bf16(a, Wz[it], az, 0, 0, 0);
      ar = __builtin_amdgcn_mfma_f32_16x16x32_bf16(a, Wr[it], ar, 0, 0, 0);
    }
    if (kh) {
#pragma unroll
      for (int j = 0; j < 4; ++j) { red[0][ct][j][lane] = az[j]; red[1][ct][j][lane] = ar[j]; }
    }
    __syncthreads();   // barrier #2: drains vmcnt -> poison globally visible
    if (!kh && owner) {
      unsigned long long sd = 0;
#pragma unroll
      for (int i = 0; i < 4; ++i) {
        float z = 1.f / (1.f + __expf(-(az[i] + red[0][ct][i][lane] + bzv)));
        float r = 1.f / (1.f + __expf(-(ar[i] + red[1][ct][i][lane] + brv)));
        zreg[i] = z;
        sd |= (unsigned long long)f2b(r * h_own[i]) << (16 * i);
      }
      // ONE 8B atomic exchange commits rows orow0..+3 of col colN (MALL RMW)
      (void)__hip_atomic_exchange((unsigned long long*)(sbR + colN * 8 + orow0),
                                  sd, __ATOMIC_RELAXED, __HIP_MEMORY_SCOPE_AGENT);
    }

    // ======== phase B: h_tilde, h(t+1) ========
    f32x4 ac = {0.f, 0.f, 0.f, 0.f};
    if (kh) {
#pragma unroll
      for (int it = 0; it < 2; ++it) {
        ac = __builtin_amdgcn_mfma_f32_16x16x32_bf16(ld8(au + it * 32), ld8(wuh + it * 32), ac, 0, 0, 0);
      }
    }
    PSTAGE(sbR);                                         // s(t) poll+stage
    REPOISON(p.hb + (size_t)sP * SLOTN + rg * GROW * NHID);  // retire h slot t+3 (issue)
    LDS_BARRIER();

#pragma unroll
    for (int it = 0; it < 16; ++it) {
      ac = __builtin_amdgcn_mfma_f32_16x16x32_bf16(LDSA(it), Wh[it], ac, 0, 0, 0);
    }
    if (kh) {
#pragma unroll
      for (int j = 0; j < 4; ++j) red[0][ct][j][lane] = ac[j];
    }
    __syncthreads();   // drains vmcnt -> poison visible before h-commit
    if (!kh && owner) {
      unsigned long long hd = 0;
#pragma unroll
      for (int i = 0; i < 4; ++i) {
        float x = ac[i] + red[0][ct][i][lane] + bhv;
        float e = __expf(2.f * x);
        float ht = 1.f - 2.f / (e + 1.f);          // tanh, overflow-safe
        float hn = (1.f - zreg[i]) * h_own[i] + zreg[i] * ht;
        h_own[i] = hn;
        hd |= (unsigned long long)f2b(hn) << (16 * i);
      }
      unsigned short* hbW = p.hb + (size_t)sW * SLOTN + rg * GROW * NHID;
      (void)__hip_atomic_exchange((unsigned long long*)(hbW + colN * 8 + orow0),
                                  hd, __ATOMIC_RELAXED, __HIP_MEMORY_SCOPE_AGENT);
      if (t == TSTEPS - 1) {
#pragma unroll
        for (int i = 0; i < 4; ++i)
          p.h[(size_t)(rg * GROW + orow0 + i) * NHID + colN] = h_own[i];
      }
    }
  }
#undef PSTAGE
#undef REPOISON
#undef LDS_BARRIER
#undef LDSA
}

// out[c*R + r] = bf16(in[r*C + c])  (W[k][n] -> WT[n][k])
__global__ void k_transpose_bf16(const float* in, unsigned short* out, int R, int C) {
  int idx = blockIdx.x * 256 + threadIdx.x;
  if (idx < R * C) {
    int r = idx / C, c = idx % C;
    out[(size_t)c * R + r] = f2b(in[idx]);
  }
}

__global__ void k_convert_bf16(const float* in, unsigned short* out, int n) {
  for (int i = blockIdx.x * 256 + threadIdx.x; i < n; i += gridDim.x * 256)
    out[i] = f2b(in[i]);
}

// logits = h_final @ W_hy + b_y ; one block (64 lanes) per batch row
__global__ void k_logits(const float* __restrict__ h, const float* __restrict__ Why,
                         const float* __restrict__ by, float* __restrict__ out) {
  int row = blockIdx.x;
  int lane = threadIdx.x;
  float acc[10];
#pragma unroll
  for (int j = 0; j < 10; ++j) acc[j] = 0.f;
  for (int k = lane; k < NHID; k += 64) {
    float hv = h[row * NHID + k];
#pragma unroll
    for (int j = 0; j < 10; ++j) acc[j] += hv * Why[k * 10 + j];
  }
#pragma unroll
  for (int j = 0; j < 10; ++j)
    for (int off = 32; off; off >>= 1) acc[j] += __shfl_down(acc[j], off);
  if (lane == 0) {
#pragma unroll
    for (int j = 0; j < 10; ++j) out[row * 10 + j] = acc[j] + by[j];
  }
}

extern "C" void kernel_launch(void* const* d_in, const int* in_sizes, int n_in,
                              void* d_out, int out_size, void* d_ws, size_t ws_size,
                              hipStream_t stream) {
  (void)in_sizes; (void)n_in; (void)out_size; (void)ws_size;
  const float* u   = (const float*)d_in[0];
  const float* Wuz = (const float*)d_in[1];
  const float* Whz = (const float*)d_in[2];
  const float* bz  = (const float*)d_in[3];
  const float* Wur = (const float*)d_in[4];
  const float* Whr = (const float*)d_in[5];
  const float* br  = (const float*)d_in[6];
  const float* Wuh = (const float*)d_in[7];
  const float* Whh = (const float*)d_in[8];
  const float* bh  = (const float*)d_in[9];
  const float* Why = (const float*)d_in[10];
  const float* by  = (const float*)d_in[11];

  char* ws = (char*)d_ws;
  size_t off = 0;
  auto alloc = [&](size_t bytes) { char* p = ws + off; off += (bytes + 255) & ~255ull; return p; };
  unsigned short* WhzT = (unsigned short*)alloc((size_t)NHID * NHID * 2);
  unsigned short* WhrT = (unsigned short*)alloc((size_t)NHID * NHID * 2);
  unsigned short* WhhT = (unsigned short*)alloc((size_t)NHID * NHID * 2);
  unsigned short* WuzT = (unsigned short*)alloc((size_t)NHID * NIN * 2);
  unsigned short* WurT = (unsigned short*)alloc((size_t)NHID * NIN * 2);
  unsigned short* WuhT = (unsigned short*)alloc((size_t)NHID * NIN * 2);
  unsigned short* ub   = (unsigned short*)alloc((size_t)TSTEPS * NB * NIN * 2);
  unsigned short* hb   = (unsigned short*)alloc(4ull * SLOTN * 2);
  unsigned short* sb   = (unsigned short*)alloc(4ull * SLOTN * 2);

  float* out = (float*)d_out;
  float* hf  = out + NB * 10;   // h_final region of d_out

  int n1 = NHID * NHID;
  hipLaunchKernelGGL(k_transpose_bf16, dim3((n1 + 255) / 256), dim3(256), 0, stream, Whz, WhzT, NHID, NHID);
  hipLaunchKernelGGL(k_transpose_bf16, dim3((n1 + 255) / 256), dim3(256), 0, stream, Whr, WhrT, NHID, NHID);
  hipLaunchKernelGGL(k_transpose_bf16, dim3((n1 + 255) / 256), dim3(256), 0, stream, Whh, WhhT, NHID, NHID);
  int n2 = NIN * NHID;
  hipLaunchKernelGGL(k_transpose_bf16, dim3((n2 + 255) / 256), dim3(256), 0, stream, Wuz, WuzT, NIN, NHID);
  hipLaunchKernelGGL(k_transpose_bf16, dim3((n2 + 255) / 256), dim3(256), 0, stream, Wur, WurT, NIN, NHID);
  hipLaunchKernelGGL(k_transpose_bf16, dim3((n2 + 255) / 256), dim3(256), 0, stream, Wuh, WuhT, NIN, NHID);
  int n3 = TSTEPS * NB * NIN;
  hipLaunchKernelGGL(k_convert_bf16, dim3(2048), dim3(256), 0, stream, u, ub, n3);
  // Slot init each launch (deterministic under graph replay):
  // hb slot 0 = real h0 = 0; hb slots 1-3 and all sb slots = 0xFFFF poison.
  hipMemsetAsync(hb, 0, (size_t)SLOTN * 2, stream);
  hipMemsetAsync(hb + SLOTN, 0xFF, 3ull * SLOTN * 2, stream);
  hipMemsetAsync(sb, 0xFF, 4ull * SLOTN * 2, stream);

  GruParams p;
  p.u = ub; p.WhzT = WhzT; p.WhrT = WhrT; p.WhhT = WhhT;
  p.WuzT = WuzT; p.WurT = WurT; p.WuhT = WuhT;
  p.bz = bz; p.br = br; p.bh = bh;
  p.h = hf; p.hb = hb; p.sb = sb;
  hipLaunchKernelGGL(gru_main, dim3(NBLK), dim3(NTHR), 0, stream, p);

  hipLaunchKernelGGL(k_logits, dim3(NB), dim3(64), 0, stream, hf, Why, by, out);
}